// Round 1
// baseline (1089.608 us; speedup 1.0000x reference)
//
#include <hip/hip_runtime.h>

// ---------- helpers ----------
__device__ __forceinline__ float bf2f(unsigned short u) {
  union { unsigned int i; float f; } v; v.i = ((unsigned int)u) << 16; return v.f;
}
__device__ __forceinline__ unsigned short f2bf(float f) {
  union { float f; unsigned int i; } v; v.f = f;
  return (unsigned short)((v.i + 0x7fffu + ((v.i >> 16) & 1u)) >> 16);
}
__device__ __forceinline__ float ftanh(float x) {
  float e = __expf(2.f * x);
  return 1.f - 2.f / (e + 1.f);
}

// ---------- weight permutation ----------
// W1p[(loc*64+o)*128 + (k*2+l)*32 + c] = W1[(loc*64+o)*128 + c*4 + k*2+l]
// W2p[(loc*128+o)*1600 + (k*5+l)*64 + c] = W2[(loc*128+o)*1600 + c*25 + k*5+l]
__global__ __launch_bounds__(256) void k_permute(const float* __restrict__ W1,
                                                 const float* __restrict__ W2,
                                                 float* __restrict__ W1p,
                                                 float* __restrict__ W2p) {
  int idx = blockIdx.x * 256 + threadIdx.x;
  if (idx < 819200) {
    int row = idx >> 7, f = idx & 127;
    int kl = f >> 5, c = f & 31;
    W1p[idx] = W1[(row << 7) + (c << 2) + kl];
  } else {
    int j = idx - 819200;
    int row = j / 1600;
    int f = j - row * 1600;
    int kl5 = f >> 6, c = f & 63;
    W2p[j] = W2[row * 1600 + c * 25 + kl5];
  }
}

// ---------- layer 0: 400 GEMMs [4096x54]*[54x32], tanh, bf16 out ----------
// h0 layout: [b][loc1(10x10)][kl(2x2)][c(32)]  (= what L1 wants contiguous)
// block 128 thr; grid (16 batch-tiles of 256, 400 locs)
__global__ __launch_bounds__(128) void k_l0(const float* __restrict__ x,
                                            const float* __restrict__ W0,
                                            const float* __restrict__ B0,
                                            unsigned short* __restrict__ h0) {
  const int t   = threadIdx.x;
  const int b0  = blockIdx.x << 8;
  const int loc = blockIdx.y;
  const int i = loc / 20, j = loc - (loc / 20) * 20;

  __shared__ __align__(16) float          sW[32 * 60];   // K padded 54->56, stride 60
  __shared__ __align__(16) unsigned short sP[256 * 60];  // bf16 patches
  __shared__ float sB[32];
  __shared__ int   sOffs[54];

  if (t < 54) {
    int c = t / 9, rr = t - c * 9;
    int r = rr / 3, l = rr - r * 3;
    sOffs[t] = c * 3600 + r * 60 + l;
  }
  for (int e = t; e < 1728; e += 128) sW[(e / 54) * 60 + (e % 54)] = W0[loc * 1728 + e];
  for (int e = t; e < 192;  e += 128) sW[(e / 6) * 60 + 54 + (e % 6)] = 0.f;
  if (t < 32) sB[t] = B0[loc * 32 + t];
  __syncthreads();

  {
    const float* xb = x + (size_t)b0 * 21600 + (3 * i) * 60 + 3 * j;
    int b = t / 54, kk = t - (t / 54) * 54;
    for (int it = 0; it < 108; ++it) {           // 256*54 elems / 128 thr
      sP[b * 60 + kk] = f2bf(xb[b * 21600 + sOffs[kk]]);
      b += 2; kk += 20;
      if (kk >= 54) { kk -= 54; b += 1; }
    }
  }
  for (int e = t; e < 1536; e += 128) sP[(e / 6) * 60 + 54 + (e % 6)] = 0;
  __syncthreads();

  const int bl  = t & 31;          // b = bl + 32r
  const int co8 = (t >> 5) << 3;   // 8 contiguous couts
  float acc[8][8] = {};
  for (int kk = 0; kk < 56; kk += 4) {
    float4 wv[8];
#pragma unroll
    for (int u = 0; u < 8; ++u) wv[u] = *(const float4*)&sW[(co8 + u) * 60 + kk];
#pragma unroll
    for (int r = 0; r < 8; ++r) {
      ushort4 av = *(const ushort4*)&sP[(bl + (r << 5)) * 60 + kk];
      float ax = bf2f(av.x), ay = bf2f(av.y), az = bf2f(av.z), aw = bf2f(av.w);
#pragma unroll
      for (int u = 0; u < 8; ++u) {
        acc[r][u] = fmaf(ax, wv[u].x, acc[r][u]);
        acc[r][u] = fmaf(ay, wv[u].y, acc[r][u]);
        acc[r][u] = fmaf(az, wv[u].z, acc[r][u]);
        acc[r][u] = fmaf(aw, wv[u].w, acc[r][u]);
      }
    }
  }

  const int o_off = (((i >> 1) * 10 + (j >> 1)) << 7) + (((i & 1) * 2 + (j & 1)) << 5) + co8;
#pragma unroll
  for (int r = 0; r < 8; ++r) {
    const int b = b0 + bl + (r << 5);
    unsigned short q[8];
#pragma unroll
    for (int u = 0; u < 8; ++u) q[u] = f2bf(ftanh(acc[r][u] + sB[co8 + u]));
    uint4 pv;
    pv.x = q[0] | ((unsigned)q[1] << 16);
    pv.y = q[2] | ((unsigned)q[3] << 16);
    pv.z = q[4] | ((unsigned)q[5] << 16);
    pv.w = q[6] | ((unsigned)q[7] << 16);
    *(uint4*)&h0[(size_t)b * 12800 + o_off] = pv;
  }
}

// ---------- layer 1: 100 GEMMs [4096x128]*[128x64], tanh, bf16 out ----------
// h1 layout: [b][loc2(2x2)][kl5(5x5)][c(64)]
// block 128 thr; grid (32 batch-tiles of 128, 100 locs)
__global__ __launch_bounds__(128) void k_l1(const unsigned short* __restrict__ h0,
                                            const float* __restrict__ W1p,
                                            const float* __restrict__ B1,
                                            unsigned short* __restrict__ h1) {
  const int t   = threadIdx.x;
  const int b0  = blockIdx.x << 7;
  const int loc = blockIdx.y;
  const int i = loc / 10, j = loc - (loc / 10) * 10;

  __shared__ __align__(16) unsigned short sA[128 * 136];  // bf16, stride 136 (272B = 17*16)
  __shared__ __align__(16) float          sW[64 * 132];   // fp32, stride 132 (528B = 33*16)
  __shared__ float sB[64];

  for (int e = t; e < 2048; e += 128) {       // A: 128 rows x 16 uint4
    int b = e >> 4, c16 = e & 15;
    *(uint4*)&sA[b * 136 + (c16 << 3)] =
        *(const uint4*)&h0[(size_t)(b0 + b) * 12800 + (loc << 7) + (c16 << 3)];
  }
  for (int e = t; e < 2048; e += 128) {       // W: 64 rows x 32 float4
    int o = e >> 5, c4 = e & 31;
    *(float4*)&sW[o * 132 + (c4 << 2)] =
        *(const float4*)&W1p[(size_t)((loc * 64 + o) * 128) + (c4 << 2)];
  }
  if (t < 64) sB[t] = B1[(loc << 6) + t];
  __syncthreads();

  const int bl = t & 15;     // b = bl + 16r
  const int og = t >> 4;     // o = og + 8u (strided to dodge bank conflicts)
  float acc[8][8] = {};
  for (int kk = 0; kk < 128; kk += 4) {
    float4 wv[8];
#pragma unroll
    for (int u = 0; u < 8; ++u) wv[u] = *(const float4*)&sW[(og + (u << 3)) * 132 + kk];
#pragma unroll
    for (int r = 0; r < 8; ++r) {
      ushort4 av = *(const ushort4*)&sA[(bl + (r << 4)) * 136 + kk];
      float ax = bf2f(av.x), ay = bf2f(av.y), az = bf2f(av.z), aw = bf2f(av.w);
#pragma unroll
      for (int u = 0; u < 8; ++u) {
        acc[r][u] = fmaf(ax, wv[u].x, acc[r][u]);
        acc[r][u] = fmaf(ay, wv[u].y, acc[r][u]);
        acc[r][u] = fmaf(az, wv[u].z, acc[r][u]);
        acc[r][u] = fmaf(aw, wv[u].w, acc[r][u]);
      }
    }
  }
  __syncthreads();
  // restage through LDS (reuse sA) so global stores are 16B-coalesced
  unsigned short* sOut = sA;   // [128][72], 144B rows (9*16)
#pragma unroll
  for (int r = 0; r < 8; ++r) {
    int b = bl + (r << 4);
#pragma unroll
    for (int u = 0; u < 8; ++u) {
      int o = og + (u << 3);
      sOut[b * 72 + o] = f2bf(ftanh(acc[r][u] + sB[o]));
    }
  }
  __syncthreads();
  const int loc2 = (i / 5) * 2 + (j / 5);
  const int kl5  = (i % 5) * 5 + (j % 5);
  const int o_off1 = loc2 * 1600 + (kl5 << 6);
  for (int e = t; e < 1024; e += 128) {
    int b = e >> 3, c8 = e & 7;
    *(uint4*)&h1[(size_t)(b0 + b) * 6400 + o_off1 + (c8 << 3)] =
        *(const uint4*)&sOut[b * 72 + (c8 << 3)];
  }
}

// ---------- layer 2: 4 GEMMs [4096x1600]*[1600x128], K-split x4, fp32 partials ----------
// block 256 thr; grid (32 batch-tiles of 128, 4 k-splits, 4 locs)
__global__ __launch_bounds__(256) void k_l2(const unsigned short* __restrict__ h1,
                                            const float* __restrict__ W2p,
                                            float* __restrict__ h2p) {
  const int t   = threadIdx.x;
  const int b0  = blockIdx.x << 7;
  const int ks  = blockIdx.y;
  const int loc = blockIdx.z;

  __shared__ __align__(16) unsigned short sA[128 * 88];   // bf16, 176B rows
  __shared__ __align__(16) float          sW[128 * 84];   // fp32, 336B rows

  const int bl = t & 15;     // b = bl + 16r
  const int og = t >> 4;     // o = og + 16u
  float acc[8][8] = {};

  for (int kt = 0; kt < 5; ++kt) {
    const int f0 = ks * 400 + kt * 80;
    __syncthreads();
    for (int e = t; e < 1280; e += 256) {      // A: 128 rows x 10 uint4
      int b = e / 10, c = e - b * 10;
      *(uint4*)&sA[b * 88 + (c << 3)] =
          *(const uint4*)&h1[(size_t)(b0 + b) * 6400 + loc * 1600 + f0 + (c << 3)];
    }
    for (int e = t; e < 2560; e += 256) {      // W: 128 rows x 20 float4
      int o = e / 20, c = e - o * 20;
      *(float4*)&sW[o * 84 + (c << 2)] =
          *(const float4*)&W2p[(size_t)(loc * 128 + o) * 1600 + f0 + (c << 2)];
    }
    __syncthreads();
    for (int kk = 0; kk < 80; kk += 4) {
      float4 wv[8];
#pragma unroll
      for (int u = 0; u < 8; ++u) wv[u] = *(const float4*)&sW[(og + (u << 4)) * 84 + kk];
#pragma unroll
      for (int r = 0; r < 8; ++r) {
        ushort4 av = *(const ushort4*)&sA[(bl + (r << 4)) * 88 + kk];
        float ax = bf2f(av.x), ay = bf2f(av.y), az = bf2f(av.z), aw = bf2f(av.w);
#pragma unroll
        for (int u = 0; u < 8; ++u) {
          acc[r][u] = fmaf(ax, wv[u].x, acc[r][u]);
          acc[r][u] = fmaf(ay, wv[u].y, acc[r][u]);
          acc[r][u] = fmaf(az, wv[u].z, acc[r][u]);
          acc[r][u] = fmaf(aw, wv[u].w, acc[r][u]);
        }
      }
    }
  }
  // partials: [ks*4+loc][b][o]
  const size_t pbase = (size_t)(ks * 4 + loc) * 4096 * 128;
#pragma unroll
  for (int r = 0; r < 8; ++r) {
    int b = b0 + bl + (r << 4);
#pragma unroll
    for (int u = 0; u < 8; ++u)
      h2p[pbase + (size_t)b * 128 + og + (u << 4)] = acc[r][u];
  }
}

// ---------- reduce k-splits + bias + tanh -> h2[b][o*4+loc] ----------
__global__ __launch_bounds__(256) void k_l2red(const float* __restrict__ h2p,
                                               const float* __restrict__ B2,
                                               float* __restrict__ h2) {
  int idx = blockIdx.x * 256 + threadIdx.x;   // 4096*128
  int b = idx >> 7, o = idx & 127;
  float s0 = 0.f, s1 = 0.f, s2 = 0.f, s3 = 0.f;
  const size_t P = (size_t)4096 * 128;
#pragma unroll
  for (int ks = 0; ks < 4; ++ks) {
    size_t base = (size_t)(ks * 4) * P + (size_t)b * 128 + o;
    s0 += h2p[base];
    s1 += h2p[base + P];
    s2 += h2p[base + 2 * P];
    s3 += h2p[base + 3 * P];
  }
  float4 v;
  v.x = ftanh(s0 + B2[o]);
  v.y = ftanh(s1 + B2[128 + o]);
  v.z = ftanh(s2 + B2[256 + o]);
  v.w = ftanh(s3 + B2[384 + o]);
  *(float4*)&h2[(size_t)b * 512 + (o << 2)] = v;
}

// ---------- classifier + softmax: one wave per sample ----------
__global__ __launch_bounds__(256) void k_cls(const float* __restrict__ h2,
                                             const float* __restrict__ info,
                                             const float* __restrict__ Wc,
                                             const float* __restrict__ bc,
                                             float* __restrict__ out) {
  const int l = threadIdx.x & 63;
  const int b = blockIdx.x * 4 + (threadIdx.x >> 6);
  const float* hrow = h2 + (size_t)b * 512;
  float p0 = 0.f, p1 = 0.f;
#pragma unroll
  for (int f = 0; f < 512; f += 64) {
    float h = hrow[f + l];
    p0 = fmaf(h, Wc[2 * (f + l)], p0);
    p1 = fmaf(h, Wc[2 * (f + l) + 1], p1);
  }
#pragma unroll
  for (int m = 32; m; m >>= 1) {
    p0 += __shfl_xor(p0, m, 64);
    p1 += __shfl_xor(p1, m, 64);
  }
  if (l == 0) {
    float i0 = info[2 * b], i1 = info[2 * b + 1];
    float l0 = p0 + i0 * Wc[1024] + i1 * Wc[1026] + bc[0];
    float l1 = p1 + i0 * Wc[1025] + i1 * Wc[1027] + bc[1];
    float mx = fmaxf(l0, l1);
    float e0 = __expf(l0 - mx), e1 = __expf(l1 - mx);
    float inv = 1.f / (e0 + e1);
    out[2 * b]     = e0 * inv;
    out[2 * b + 1] = e1 * inv;
  }
}

extern "C" void kernel_launch(void* const* d_in, const int* in_sizes, int n_in,
                              void* d_out, int out_size, void* d_ws, size_t ws_size,
                              hipStream_t stream) {
  const float* x    = (const float*)d_in[0];
  const float* info = (const float*)d_in[1];
  const float* W0   = (const float*)d_in[2];
  const float* B0   = (const float*)d_in[3];
  const float* W1   = (const float*)d_in[4];
  const float* B1   = (const float*)d_in[5];
  const float* W2   = (const float*)d_in[6];
  const float* B2   = (const float*)d_in[7];
  const float* Wc   = (const float*)d_in[8];
  const float* bc   = (const float*)d_in[9];
  float* out = (float*)d_out;

  // ws layout (172.2 MB total):
  //   [0, 104857600)           h0 bf16 [4096][12800]   (dead after k_l1 -> reused by h2p)
  //   [0, 33554432)            h2p fp32 [16][4096][128] (aliases h0, written in k_l2)
  //   [104857600, +52428800)   h1 bf16 [4096][6400]
  //   [157286400, +8388608)    h2 fp32 [4096][512]
  //   [165675008, +3276800)    W1p fp32
  //   [168951808, +3276800)    W2p fp32
  char* ws = (char*)d_ws;
  unsigned short* h0 = (unsigned short*)ws;
  float*          h2p = (float*)ws;
  unsigned short* h1 = (unsigned short*)(ws + 104857600);
  float*          h2 = (float*)(ws + 104857600 + 52428800);
  float*          W1p = (float*)(ws + 104857600 + 52428800 + 8388608);
  float*          W2p = (float*)(ws + 104857600 + 52428800 + 8388608 + 3276800);

  k_permute<<<dim3(6400),       dim3(256), 0, stream>>>(W1, W2, W1p, W2p);
  k_l0     <<<dim3(16, 400),    dim3(128), 0, stream>>>(x, W0, B0, h0);
  k_l1     <<<dim3(32, 100),    dim3(128), 0, stream>>>(h0, W1p, B1, h1);
  k_l2     <<<dim3(32, 4, 4),   dim3(256), 0, stream>>>(h1, W2p, h2p);
  k_l2red  <<<dim3(2048),       dim3(256), 0, stream>>>(h2p, B2, h2);
  k_cls    <<<dim3(1024),       dim3(256), 0, stream>>>(h2, info, Wc, bc, out);
}